// Round 1
// baseline (49.387 us; speedup 1.0000x reference)
//
#include <hip/hip_runtime.h>
#include <math.h>

#define NB   64
#define H_   384
#define W_   384
#define NR   12
#define NC   12
#define NP   144     // patches per batch
#define PE   1024    // elements per patch
#define NSEL 36

// ws layout:
// [0,256):    uint umin[64]
// [256,512):  uint umax[64]
// [512, 512 + 64*144*1024): uint8 binned patches [B][144][1024]

__device__ inline unsigned int f2s(float f){
    unsigned int b = __float_as_uint(f);
    return (b & 0x80000000u) ? ~b : (b | 0x80000000u);
}
__device__ inline float s2f(unsigned int u){
    unsigned int b = (u & 0x80000000u) ? (u & 0x7FFFFFFFu) : ~u;
    return __uint_as_float(b);
}

__global__ __launch_bounds__(256) void k_minmax(const float* __restrict__ sino,
                                                unsigned int* __restrict__ umin,
                                                unsigned int* __restrict__ umax){
    int b = blockIdx.x >> 3;
    int part = blockIdx.x & 7;
    const float4* src = (const float4*)(sino + (size_t)b * (H_ * W_));
    int base = part * 4608 + threadIdx.x;   // 36864 float4 / batch, 4608 / part
    float mn = 1e30f, mx = -1e30f;
    #pragma unroll
    for (int k = 0; k < 18; k++){
        float4 v = src[base + k * 256];
        mn = fminf(mn, fminf(fminf(v.x, v.y), fminf(v.z, v.w)));
        mx = fmaxf(mx, fmaxf(fmaxf(v.x, v.y), fmaxf(v.z, v.w)));
    }
    #pragma unroll
    for (int off = 32; off > 0; off >>= 1){
        mn = fminf(mn, __shfl_down(mn, off));
        mx = fmaxf(mx, __shfl_down(mx, off));
    }
    __shared__ float smn[4], smx[4];
    int lane = threadIdx.x & 63, wv = threadIdx.x >> 6;
    if (lane == 0){ smn[wv] = mn; smx[wv] = mx; }
    __syncthreads();
    if (threadIdx.x == 0){
        mn = fminf(fminf(smn[0], smn[1]), fminf(smn[2], smn[3]));
        mx = fmaxf(fmaxf(smx[0], smx[1]), fmaxf(smx[2], smx[3]));
        atomicMin(&umin[b], f2s(mn));
        atomicMax(&umax[b], f2s(mx));
    }
}

__device__ inline int binval(float x, float mn, float denom){
    float nrm = (x - mn) / denom;                 // mirror reference op order exactly
    nrm = fminf(fmaxf(nrm, 0.0f), 1.0f);
    int bn = (int)(nrm * 63.0f);                  // truncation, like astype(int32)
    bn = bn < 0 ? 0 : (bn > 63 ? 63 : bn);
    return bn;
}

__global__ __launch_bounds__(256) void k_bin(const float* __restrict__ sino,
                                             const unsigned int* __restrict__ umin,
                                             const unsigned int* __restrict__ umax,
                                             unsigned char* __restrict__ pat){
    // one block per (b, patch); 256 threads * 4 bytes = 1024 = one patch
    int b = blockIdx.x / NP;
    int p = blockIdx.x % NP;
    int pr = p / NC, pc = p % NC;
    float mn = s2f(umin[b]);
    float mx = s2f(umax[b]);
    float denom = mx - mn + 1e-6f;
    int tid = threadIdx.x;
    int i  = tid >> 3;            // row in patch (32 rows, 8 threads/row)
    int j4 = (tid & 7) << 2;      // col in patch, multiple of 4
    const float* rowp = sino + ((size_t)b * H_ + (size_t)(pr * 32 + i)) * W_ + pc * 32 + j4;
    float4 v = *(const float4*)rowp;
    uchar4 o;
    o.x = (unsigned char)binval(v.x, mn, denom);
    o.y = (unsigned char)binval(v.y, mn, denom);
    o.z = (unsigned char)binval(v.z, mn, denom);
    o.w = (unsigned char)binval(v.w, mn, denom);
    *(uchar4*)(pat + (size_t)blockIdx.x * PE + tid * 4) = o;
}

__device__ inline unsigned int bytesad(unsigned int a, unsigned int b){
    unsigned int s = 0;
    #pragma unroll
    for (int k = 0; k < 4; k++){
        int av = (a >> (8 * k)) & 255;
        int bv = (b >> (8 * k)) & 255;
        int d = av - bv;
        s += (unsigned int)(d < 0 ? -d : d);
    }
    return s;
}

__global__ __launch_bounds__(256) void k_mi(const unsigned char* __restrict__ pat,
                                            float* __restrict__ out){
    int b = blockIdx.x / NSEL;
    int s = blockIdx.x % NSEL;
    int sr = (s / 6) * 2, sc = (s % 6) * 2;
    int pself = sr * NC + sc;
    const unsigned char* batch = pat + (size_t)b * NP * PE;

    __shared__ uint4 selw4[64];            // selected patch, 1024 bytes
    __shared__ unsigned int hist[4096];    // 64x64 joint histogram
    __shared__ unsigned int distArr[25];
    __shared__ int bestCid;
    __shared__ float sH[8];                // [0]=hx [1]=hy [4..7]=hxy wave partials

    int tid = threadIdx.x;
    int lane = tid & 63, wv = tid >> 6;

    #pragma unroll
    for (int k = 0; k < 16; k++) hist[k * 256 + tid] = 0;
    ((unsigned int*)selw4)[tid] = ((const unsigned int*)(batch + (size_t)pself * PE))[tid];
    __syncthreads();

    // distances: wave wv handles candidates c = wv, wv+4, ...
    for (int c = wv; c < 25; c += 4){
        int dr = c / 5 - 2, dc = c % 5 - 2;
        int rr = min(max(sr + dr, 0), NR - 1);
        int cc = min(max(sc + dc, 0), NC - 1);
        int cid = rr * NC + cc;
        unsigned int dist = 0xFFFFFFFFu;   // masked (self) sentinel
        if (cid != pself){
            uint4 cv = ((const uint4*)(batch + (size_t)cid * PE))[lane];
            uint4 sv = selw4[lane];
            dist = bytesad(cv.x, sv.x) + bytesad(cv.y, sv.y)
                 + bytesad(cv.z, sv.z) + bytesad(cv.w, sv.w);
            #pragma unroll
            for (int off = 32; off > 0; off >>= 1) dist += __shfl_down(dist, off);
        }
        if (lane == 0) distArr[c] = dist;
    }
    __syncthreads();

    if (tid == 0){
        unsigned int bd = 0xFFFFFFFFu; int bc = 0;
        #pragma unroll
        for (int c = 0; c < 25; c++){
            if (distArr[c] < bd){ bd = distArr[c]; bc = c; }   // strict <: first-min like argmin
        }
        int dr = bc / 5 - 2, dc = bc % 5 - 2;
        int rr = min(max(sr + dr, 0), NR - 1);
        int cc = min(max(sc + dc, 0), NC - 1);
        bestCid = rr * NC + cc;
    }
    __syncthreads();

    // joint histogram: each thread handles 4 elements
    {
        unsigned int bw = ((const unsigned int*)(batch + (size_t)bestCid * PE))[tid];
        unsigned int sw = ((const unsigned int*)selw4)[tid];
        #pragma unroll
        for (int k = 0; k < 4; k++){
            unsigned int sv = (sw >> (8 * k)) & 255u;
            unsigned int bv = (bw >> (8 * k)) & 255u;
            atomicAdd(&hist[sv * 64 + bv], 1u);
        }
    }
    __syncthreads();

    const float invP = 1.0f / 1024.0f;
    // h_xy partial: 16 bins per thread, coalesced bank access
    float part = 0.0f;
    #pragma unroll
    for (int k = 0; k < 16; k++){
        unsigned int cnt = hist[k * 256 + tid];
        float pj = (float)cnt * invP;
        part -= pj * logf(pj + 1e-8f);     // cnt==0 -> -0*log(1e-8) == 0
    }
    #pragma unroll
    for (int off = 32; off > 0; off >>= 1) part += __shfl_down(part, off);
    if (lane == 0) sH[4 + wv] = part;

    // marginals: wave0 -> p_x (row sums), wave1 -> p_y (col sums); diagonal reads avoid bank conflicts
    if (tid < 128){
        int isY = tid >> 6;
        int t = tid & 63;
        unsigned int cnt = 0;
        if (!isY){
            for (int k = 0; k < 64; k++) cnt += hist[t * 64 + ((k + t) & 63)];
        } else {
            for (int k = 0; k < 64; k++) cnt += hist[((k + t) & 63) * 64 + t];
        }
        float pm = (float)cnt * invP;
        float term = -pm * logf(pm + 1e-8f);
        #pragma unroll
        for (int off = 32; off > 0; off >>= 1) term += __shfl_down(term, off);
        if (t == 0) sH[isY] = term;
    }
    __syncthreads();

    if (tid == 0){
        float hx = sH[0], hy = sH[1];
        float hxy = sH[4] + sH[5] + sH[6] + sH[7];
        float mi = hx + hy - hxy;
        out[blockIdx.x] = log1pf(mi);
    }
}

extern "C" void kernel_launch(void* const* d_in, const int* in_sizes, int n_in,
                              void* d_out, int out_size, void* d_ws, size_t ws_size,
                              hipStream_t stream) {
    const float* sino = (const float*)d_in[0];
    float* out = (float*)d_out;
    unsigned char* ws = (unsigned char*)d_ws;
    unsigned int* umin = (unsigned int*)ws;
    unsigned int* umax = (unsigned int*)(ws + 256);
    unsigned char* pat = ws + 512;

    hipMemsetAsync(umin, 0xFF, 256, stream);
    hipMemsetAsync(umax, 0x00, 256, stream);

    k_minmax<<<NB * 8, 256, 0, stream>>>(sino, umin, umax);
    k_bin<<<NB * NP, 256, 0, stream>>>(sino, umin, umax, pat);
    k_mi<<<NB * NSEL, 256, 0, stream>>>(pat, out);
}

// Round 2
// 38.469 us; speedup vs baseline: 1.2838x; 1.2838x over previous
//
#include <hip/hip_runtime.h>
#include <math.h>

#define NB   64
#define H_   384
#define W_   384
#define NR   12
#define NC   12
#define NP   144     // patches per batch
#define PE   1024    // elements per patch
#define NSEL 36
#define NPART 8      // min/max partials per batch

// ws layout:
// [0, 2048):            float pmin[64][8]
// [2048, 4096):         float pmax[64][8]
// [4096, 4096+64*144*1024): uint8 binned patches [B][144][1024]

__global__ __launch_bounds__(256) void k_minmax(const float* __restrict__ sino,
                                                float* __restrict__ pmin,
                                                float* __restrict__ pmax){
    int b = blockIdx.x >> 3;
    int part = blockIdx.x & 7;
    const float4* src = (const float4*)(sino + (size_t)b * (H_ * W_));
    int base = part * 4608 + threadIdx.x;   // 36864 float4 / batch, 4608 / part
    float mn = 1e30f, mx = -1e30f;
    #pragma unroll
    for (int k = 0; k < 18; k++){
        float4 v = src[base + k * 256];
        mn = fminf(mn, fminf(fminf(v.x, v.y), fminf(v.z, v.w)));
        mx = fmaxf(mx, fmaxf(fmaxf(v.x, v.y), fmaxf(v.z, v.w)));
    }
    #pragma unroll
    for (int off = 32; off > 0; off >>= 1){
        mn = fminf(mn, __shfl_down(mn, off));
        mx = fmaxf(mx, __shfl_down(mx, off));
    }
    __shared__ float smn[4], smx[4];
    int lane = threadIdx.x & 63, wv = threadIdx.x >> 6;
    if (lane == 0){ smn[wv] = mn; smx[wv] = mx; }
    __syncthreads();
    if (threadIdx.x == 0){
        mn = fminf(fminf(smn[0], smn[1]), fminf(smn[2], smn[3]));
        mx = fmaxf(fmaxf(smx[0], smx[1]), fmaxf(smx[2], smx[3]));
        pmin[b * NPART + part] = mn;   // race-free overwrite: no init needed
        pmax[b * NPART + part] = mx;
    }
}

__device__ inline int binval(float x, float mn, float denom){
    float nrm = (x - mn) / denom;                 // mirror reference op order exactly
    nrm = fminf(fmaxf(nrm, 0.0f), 1.0f);
    int bn = (int)(nrm * 63.0f);                  // truncation, like astype(int32)
    bn = bn < 0 ? 0 : (bn > 63 ? 63 : bn);
    return bn;
}

__global__ __launch_bounds__(256) void k_bin(const float* __restrict__ sino,
                                             const float* __restrict__ pmin,
                                             const float* __restrict__ pmax,
                                             unsigned char* __restrict__ pat){
    // one block per (b, patch); 256 threads * 4 bytes = 1024 = one patch
    int b = blockIdx.x / NP;
    int p = blockIdx.x % NP;
    int pr = p / NC, pc = p % NC;
    float mn = 1e30f, mx = -1e30f;
    #pragma unroll
    for (int k = 0; k < NPART; k++){              // uniform addresses -> scalar loads
        mn = fminf(mn, pmin[b * NPART + k]);
        mx = fmaxf(mx, pmax[b * NPART + k]);
    }
    float denom = mx - mn + 1e-6f;
    int tid = threadIdx.x;
    int i  = tid >> 3;            // row in patch (32 rows, 8 threads/row)
    int j4 = (tid & 7) << 2;      // col in patch, multiple of 4
    const float* rowp = sino + ((size_t)b * H_ + (size_t)(pr * 32 + i)) * W_ + pc * 32 + j4;
    float4 v = *(const float4*)rowp;
    uchar4 o;
    o.x = (unsigned char)binval(v.x, mn, denom);
    o.y = (unsigned char)binval(v.y, mn, denom);
    o.z = (unsigned char)binval(v.z, mn, denom);
    o.w = (unsigned char)binval(v.w, mn, denom);
    *(uchar4*)(pat + (size_t)blockIdx.x * PE + tid * 4) = o;
}

__device__ inline unsigned int bytesad(unsigned int a, unsigned int b, unsigned int acc){
#if __has_builtin(__builtin_amdgcn_sad_u8)
    return __builtin_amdgcn_sad_u8(a, b, acc);
#else
    unsigned int s = acc;
    #pragma unroll
    for (int k = 0; k < 4; k++){
        int av = (a >> (8 * k)) & 255;
        int bv = (b >> (8 * k)) & 255;
        int d = av - bv;
        s += (unsigned int)(d < 0 ? -d : d);
    }
    return s;
#endif
}

__global__ __launch_bounds__(256) void k_mi(const unsigned char* __restrict__ pat,
                                            float* __restrict__ out){
    int b = blockIdx.x / NSEL;
    int s = blockIdx.x % NSEL;
    int sr = (s / 6) * 2, sc = (s % 6) * 2;
    int pself = sr * NC + sc;
    const unsigned char* batch = pat + (size_t)b * NP * PE;

    __shared__ uint4 selw4[64];            // selected patch, 1024 bytes
    __shared__ unsigned int hist[4096];    // 64x64 joint histogram
    __shared__ unsigned int distArr[25];
    __shared__ int bestCid;
    __shared__ float sH[8];                // [0]=hx [1]=hy [4..7]=hxy wave partials

    int tid = threadIdx.x;
    int lane = tid & 63, wv = tid >> 6;

    #pragma unroll
    for (int k = 0; k < 16; k++) hist[k * 256 + tid] = 0;
    ((unsigned int*)selw4)[tid] = ((const unsigned int*)(batch + (size_t)pself * PE))[tid];
    __syncthreads();

    // distances: wave wv handles candidates c = wv, wv+4, ...
    for (int c = wv; c < 25; c += 4){
        int dr = c / 5 - 2, dc = c % 5 - 2;
        int rr = min(max(sr + dr, 0), NR - 1);
        int cc = min(max(sc + dc, 0), NC - 1);
        int cid = rr * NC + cc;
        unsigned int dist = 0xFFFFFFFFu;   // masked (self / clipped-onto-self) sentinel
        if (cid != pself){
            uint4 cv = ((const uint4*)(batch + (size_t)cid * PE))[lane];
            uint4 sv = selw4[lane];
            dist = bytesad(cv.x, sv.x, 0u);
            dist = bytesad(cv.y, sv.y, dist);
            dist = bytesad(cv.z, sv.z, dist);
            dist = bytesad(cv.w, sv.w, dist);
            #pragma unroll
            for (int off = 32; off > 0; off >>= 1) dist += __shfl_down(dist, off);
        }
        if (lane == 0) distArr[c] = dist;
    }
    __syncthreads();

    if (tid == 0){
        unsigned int bd = 0xFFFFFFFFu; int bc = 0;
        #pragma unroll
        for (int c = 0; c < 25; c++){
            if (distArr[c] < bd){ bd = distArr[c]; bc = c; }   // strict <: first-min like argmin
        }
        int dr = bc / 5 - 2, dc = bc % 5 - 2;
        int rr = min(max(sr + dr, 0), NR - 1);
        int cc = min(max(sc + dc, 0), NC - 1);
        bestCid = rr * NC + cc;
    }
    __syncthreads();

    // joint histogram: each thread handles 4 elements
    {
        unsigned int bw = ((const unsigned int*)(batch + (size_t)bestCid * PE))[tid];
        unsigned int sw = ((const unsigned int*)selw4)[tid];
        #pragma unroll
        for (int k = 0; k < 4; k++){
            unsigned int sv = (sw >> (8 * k)) & 255u;
            unsigned int bv = (bw >> (8 * k)) & 255u;
            atomicAdd(&hist[sv * 64 + bv], 1u);
        }
    }
    __syncthreads();

    const float invP = 1.0f / 1024.0f;
    // h_xy partial: 16 bins per thread; skip empty bins (exact: term is 0.0)
    float part = 0.0f;
    #pragma unroll
    for (int k = 0; k < 16; k++){
        unsigned int cnt = hist[k * 256 + tid];
        if (cnt){
            float pj = (float)cnt * invP;
            part -= pj * __logf(pj + 1e-8f);
        }
    }
    #pragma unroll
    for (int off = 32; off > 0; off >>= 1) part += __shfl_down(part, off);
    if (lane == 0) sH[4 + wv] = part;

    // marginals: wave0 -> p_x (row sums), wave1 -> p_y (col sums); diagonal reads avoid bank conflicts
    if (tid < 128){
        int isY = tid >> 6;
        int t = tid & 63;
        unsigned int cnt = 0;
        if (!isY){
            for (int k = 0; k < 64; k++) cnt += hist[t * 64 + ((k + t) & 63)];
        } else {
            for (int k = 0; k < 64; k++) cnt += hist[((k + t) & 63) * 64 + t];
        }
        float pm = (float)cnt * invP;
        float term = (cnt ? -pm * __logf(pm + 1e-8f) : 0.0f);
        #pragma unroll
        for (int off = 32; off > 0; off >>= 1) term += __shfl_down(term, off);
        if (t == 0) sH[isY] = term;
    }
    __syncthreads();

    if (tid == 0){
        float hx = sH[0], hy = sH[1];
        float hxy = sH[4] + sH[5] + sH[6] + sH[7];
        float mi = hx + hy - hxy;
        out[blockIdx.x] = log1pf(mi);
    }
}

extern "C" void kernel_launch(void* const* d_in, const int* in_sizes, int n_in,
                              void* d_out, int out_size, void* d_ws, size_t ws_size,
                              hipStream_t stream) {
    const float* sino = (const float*)d_in[0];
    float* out = (float*)d_out;
    unsigned char* ws = (unsigned char*)d_ws;
    float* pmin = (float*)ws;
    float* pmax = (float*)(ws + 2048);
    unsigned char* pat = ws + 4096;

    k_minmax<<<NB * NPART, 256, 0, stream>>>(sino, pmin, pmax);
    k_bin<<<NB * NP, 256, 0, stream>>>(sino, pmin, pmax, pat);
    k_mi<<<NB * NSEL, 256, 0, stream>>>(pat, out);
}